// Round 6
// baseline (313.066 us; speedup 1.0000x reference)
//
#include <hip/hip_runtime.h>

#define B_ 256
#define T_ 2048
#define F_ 20
#define NT (B_*T_)
#define CH 16
#define NCH (T_/CH)   // 128 chunks

typedef __bf16 bf16x8 __attribute__((ext_vector_type(8)));
typedef float  f32x4  __attribute__((ext_vector_type(4)));

__device__ __forceinline__ float ex2(float x){ return __builtin_amdgcn_exp2f(x); }
__device__ __forceinline__ float rcpf_(float x){ return __builtin_amdgcn_rcpf(x); }

// 20*log2(e), 2*log2(e), log2(e), ln2/20
#define K10F 28.853900817779268f
#define INVK 0.034657359027997264f
#define K1F   2.8853900817779268f
#define LOG2E 1.4426950408889634f

__device__ __forceinline__ float hside(float x){ return 1.0f - rcpf_(ex2(K10F*x) + 1.0f); }
__device__ __forceinline__ float tanh_f(float z){ return 1.0f - 2.0f*rcpf_(ex2(K1F*z) + 1.0f); }
__device__ __forceinline__ float sigmoid_f(float z){ return rcpf_(1.0f + ex2(-LOG2E*z)); }

// ws float layout (b-major, rho = b*T + t):
// wuT [0,NT) | wdT [NT,2NT) | params2 [2NT,10NT) | pT [10NT,11NT)

// Typed static LDS: distinct struct members => provable non-aliasing => the
// compiler can batch each stage's ds_reads into registers (the R4/R5 failure).
struct ScanS {
  float2 ppL[2][CH][32];   // {K*pet, K*(p-pet)}  chunk c -> slot c&1
  float  dkR[2][CH][32];   // dK   (W0 -> W1a, lag1)
  float  bsR[4][CH][32];   // BASE (W0 -> W3, lag3)
  float  wuR[2][CH][32];   // Wu'  (W0 -> wu-writer, lag1)
  float  rpR[4][CH][32];   // RP   (W1a -> W1b lag1, W3 lag2)
  float  hrR[2][CH][32];   // HRP  (W1b -> W3, lag1)
  float  qvR[4][CH][32];   // QV   (W3 -> W4 lag1, W5 lag2)
  float  b2R[4][CH][32];   // B2   (W3 -> W5, lag2)
  float  hqR[2][CH][32];   // HQ   (W4 -> W5, lag1)
  float  wdR[2][CH][32];   // WD'  (W5 -> wd-writer, lag1)
};
struct MlpS {
  __bf16 w1f[16*32*8];
  __bf16 w2f[32*64*8];
  float  b1s[256];
  float  b2s[64];
  float  w3s[512];
  float  b3s[8];
  __bf16 hbuf[8][1152];
};
union SMu { ScanS s; MlpS m; };

// blocks 0..7: 9-wave pipelined scan, 32 batches each.
// blocks 8..4103: MFMA MLP, 128 b-major rows each (8 compute waves + 1 idle).
__global__ __launch_bounds__(576) void fused_kernel(const float* __restrict__ in,
    const float* __restrict__ w1, const float* __restrict__ b1,
    const float* __restrict__ w2, const float* __restrict__ b2,
    const float* __restrict__ w3, const float* __restrict__ b3,
    float* __restrict__ ws){
  __shared__ SMu smu;
  float* params2 = ws + 2*(size_t)NT;

  if (blockIdx.x < 8) {
    ScanS& S = smu.s;
    float* wuT = ws;
    float* wdT = ws + (size_t)NT;
    float* pT  = ws + 10*(size_t)NT;
    int tid  = threadIdx.x;
    int wv   = tid >> 6;
    int lane = tid & 31;
    bool act = (tid & 63) < 32;
    int bmy  = blockIdx.x*32 + lane;
    const float* inb = in + (size_t)bmy*T_*F_;

    float Wu = 0.0f, WL = 0.0f, WD = 0.0f;   // K-scaled state
    float2 v[CH];                            // loader prefetch regs

    if (wv == 6 && act){
      // preload chunk 0, publish, write pT(0), then issue chunk-1 loads
      #pragma unroll
      for (int s = 0; s < CH; ++s){
        float4 r4 = *(const float4*)(inb + (size_t)s*F_);
        v[s] = make_float2(r4.x, r4.z);
      }
      #pragma unroll
      for (int s = 0; s < CH; ++s)
        S.ppL[0][s][lane] = make_float2(K10F*v[s].x, K10F*(v[s].y - v[s].x));
      float* pdst = &pT[(size_t)bmy*T_];
      #pragma unroll
      for (int g = 0; g < 4; ++g)
        *(float4*)(pdst + g*4) = make_float4(v[g*4].y, v[g*4+1].y, v[g*4+2].y, v[g*4+3].y);
      #pragma unroll
      for (int s = 0; s < CH; ++s){
        float4 r4 = *(const float4*)(inb + (size_t)(CH + s)*F_);
        v[s] = make_float2(r4.x, r4.z);
      }
    }
    __syncthreads();

    for (int it = 0; it < NCH + 6; ++it){
      if (wv == 0){                               // wu chain, chunk c = it
        int c = it;
        if (c < NCH && act){
          float2 pe[CH];
          #pragma unroll
          for (int s = 0; s < CH; ++s) pe[s] = S.ppL[c&1][s][lane];
          float dk_[CH], bs_[CH], wu_[CH];
          #pragma unroll
          for (int s = 0; s < CH; ++s){
            float t1 = Wu - pe[s].x;
            float r  = rcpf_(ex2(t1) + 1.0f);
            float dK = -t1*r;
            float BS = pe[s].y + dK;
            Wu += BS;
            dk_[s] = dK; bs_[s] = BS; wu_[s] = Wu;
          }
          #pragma unroll
          for (int s = 0; s < CH; ++s) S.dkR[c&1][s][lane] = dk_[s];
          #pragma unroll
          for (int s = 0; s < CH; ++s) S.bsR[c&3][s][lane] = bs_[s];
          #pragma unroll
          for (int s = 0; s < CH; ++s) S.wuR[c&1][s][lane] = wu_[s];
        }
      } else if (wv == 1){                        // RP (stateless), c = it-1
        int c = it - 1;
        if (c >= 0 && c < NCH && act){
          float dk_[CH];
          #pragma unroll
          for (int s = 0; s < CH; ++s) dk_[s] = S.dkR[c&1][s][lane];
          float rp_[CH];
          #pragma unroll
          for (int s = 0; s < CH; ++s){
            float r1 = rcpf_(ex2(dk_[s]) + 1.0f);
            rp_[s] = fmaf(-dk_[s], r1, dk_[s]);
          }
          #pragma unroll
          for (int s = 0; s < CH; ++s) S.rpR[c&3][s][lane] = rp_[s];
        }
      } else if (wv == 2){                        // HRP (stateless), c = it-2
        int c = it - 2;
        if (c >= 0 && c < NCH && act){
          float rp_[CH];
          #pragma unroll
          for (int s = 0; s < CH; ++s) rp_[s] = S.rpR[c&3][s][lane];
          float hr_[CH];
          #pragma unroll
          for (int s = 0; s < CH; ++s) hr_[s] = 1.0f - rcpf_(ex2(rp_[s]) + 1.0f);
          #pragma unroll
          for (int s = 0; s < CH; ++s) S.hrR[c&1][s][lane] = hr_[s];
        }
      } else if (wv == 3){                        // wl chain, c = it-3
        int c = it - 3;
        if (c >= 0 && c < NCH && act){
          float rp_[CH], hr_[CH], bs_[CH];
          #pragma unroll
          for (int s = 0; s < CH; ++s) rp_[s] = S.rpR[c&3][s][lane];
          #pragma unroll
          for (int s = 0; s < CH; ++s) hr_[s] = S.hrR[c&1][s][lane];
          #pragma unroll
          for (int s = 0; s < CH; ++s) bs_[s] = S.bsR[c&3][s][lane];
          float qv_[CH], b2_[CH];
          #pragma unroll
          for (int s = 0; s < CH; ++s){
            float D2   = rp_[s] - WL;
            float r    = rcpf_(ex2(D2) + 1.0f);
            float et22 = fmaf(D2, r, WL);
            float WLB  = WL + bs_[s];
            float ET2  = hr_[s]*et22;
            WL = fmaf(-hr_[s], et22, WLB);
            qv_[s] = rp_[s] - ET2;
            b2_[s] = bs_[s] - ET2;
          }
          #pragma unroll
          for (int s = 0; s < CH; ++s) S.qvR[c&3][s][lane] = qv_[s];
          #pragma unroll
          for (int s = 0; s < CH; ++s) S.b2R[c&3][s][lane] = b2_[s];
        }
      } else if (wv == 4){                        // HQ (stateless), c = it-4
        int c = it - 4;
        if (c >= 0 && c < NCH && act){
          float qv_[CH];
          #pragma unroll
          for (int s = 0; s < CH; ++s) qv_[s] = S.qvR[c&3][s][lane];
          float hq_[CH];
          #pragma unroll
          for (int s = 0; s < CH; ++s) hq_[s] = 1.0f - rcpf_(ex2(qv_[s]) + 1.0f);
          #pragma unroll
          for (int s = 0; s < CH; ++s) S.hqR[c&1][s][lane] = hq_[s];
        }
      } else if (wv == 5){                        // wd chain, c = it-5
        int c = it - 5;
        if (c >= 0 && c < NCH && act){
          float qv_[CH], hq_[CH], b2_[CH];
          #pragma unroll
          for (int s = 0; s < CH; ++s) qv_[s] = S.qvR[c&3][s][lane];
          #pragma unroll
          for (int s = 0; s < CH; ++s) hq_[s] = S.hqR[c&1][s][lane];
          #pragma unroll
          for (int s = 0; s < CH; ++s) b2_[s] = S.b2R[c&3][s][lane];
          float wd_[CH];
          #pragma unroll
          for (int s = 0; s < CH; ++s){
            float D3   = qv_[s] - WD;
            float r    = rcpf_(ex2(D3) + 1.0f);
            float et33 = fmaf(D3, r, WD);
            float WDB  = WD + b2_[s];
            WD = fmaf(-hq_[s], et33, WDB);
            wd_[s] = WD;
          }
          #pragma unroll
          for (int s = 0; s < CH; ++s) S.wdR[c&1][s][lane] = wd_[s];
        }
      } else if (wv == 6){                        // loader: publish it+1, issue it+2
        int n = it + 1;
        if (n < NCH && act){
          float2 w[CH];
          #pragma unroll
          for (int s = 0; s < CH; ++s) w[s] = v[s];   // waits the in-flight loads
          #pragma unroll
          for (int s = 0; s < CH; ++s)
            S.ppL[n&1][s][lane] = make_float2(K10F*w[s].x, K10F*(w[s].y - w[s].x));
          float* pdst = &pT[(size_t)bmy*T_ + n*CH];
          #pragma unroll
          for (int g = 0; g < 4; ++g)
            *(float4*)(pdst + g*4) = make_float4(w[g*4].y, w[g*4+1].y, w[g*4+2].y, w[g*4+3].y);
          int n2 = it + 2;
          if (n2 < NCH){
            #pragma unroll
            for (int s = 0; s < CH; ++s){
              float4 r4 = *(const float4*)(inb + (size_t)(n2*CH + s)*F_);
              v[s] = make_float2(r4.x, r4.z);
            }
          }
        }
      } else if (wv == 7){                        // wu writer, c = it-1
        int c = it - 1;
        if (c >= 0 && c < NCH && act){
          float wu_[CH];
          #pragma unroll
          for (int s = 0; s < CH; ++s) wu_[s] = S.wuR[c&1][s][lane] * INVK;
          float* dst = &wuT[(size_t)bmy*T_ + c*CH];
          #pragma unroll
          for (int g = 0; g < 4; ++g)
            *(float4*)(dst + g*4) = make_float4(wu_[g*4], wu_[g*4+1], wu_[g*4+2], wu_[g*4+3]);
        }
      } else {                                    // wv==8: wd writer, c = it-6
        int c = it - 6;
        if (c >= 0 && c < NCH && act){
          float wd_[CH];
          #pragma unroll
          for (int s = 0; s < CH; ++s) wd_[s] = S.wdR[c&1][s][lane] * INVK;
          float* dst = &wdT[(size_t)bmy*T_ + c*CH];
          #pragma unroll
          for (int g = 0; g < 4; ++g)
            *(float4*)(dst + g*4) = make_float4(wd_[g*4], wd_[g*4+1], wd_[g*4+2], wd_[g*4+3]);
        }
      }
      __syncthreads();
    }
    return;
  }

  // ================== MFMA MLP path (b-major rows) ==================
  MlpS& M = smu.m;
  int tid = threadIdx.x;

  for (int s = tid; s < 16*32*8; s += 576) M.w1f[s] = (__bf16)0.0f;
  __syncthreads();
  for (int idx = tid; idx < 15*256; idx += 576){   // w1: (k,n) k<15
    int k = idx >> 8, n = idx & 255;
    int ct = n >> 4;
    int l  = ((k>>3)*16) + (n & 15);
    int j  = k & 7;
    M.w1f[(ct*32 + l)*8 + j] = (__bf16)w1[idx];
  }
  for (int idx = tid; idx < 256*64; idx += 576){   // w2: (k,n)
    int k = idx >> 6, n = idx & 63;
    int kb = k >> 5;
    int lq = (k >> 3) & 3;
    int j  = k & 7;
    int ct = n >> 4;
    int l  = lq*16 + (n & 15);
    M.w2f[((kb*4 + ct)*64 + l)*8 + j] = (__bf16)w2[idx];
  }
  if (tid < 256) M.b1s[tid] = b1[tid];
  if (tid < 64)  M.b2s[tid] = b2[tid];
  if (tid < 512) M.w3s[tid] = w3[tid];
  if (tid < 8)   M.b3s[tid] = b3[tid];
  __syncthreads();

  int wv = tid >> 6;
  if (wv >= 8) return;                        // idle 9th wave (after barriers)
  int lane = tid & 63;
  int m    = lane & 15;
  int q    = lane >> 4;
  int r0   = (blockIdx.x - 8)*128 + wv*16;    // b-major rho

  int rho = r0 + m;
  const float* ap = in + (size_t)rho*F_ + 5;
  bf16x8 a1;
  #pragma unroll
  for (int j = 0; j < 8; ++j){
    int k = q*8 + j;
    float vv = (k < 15) ? ap[k] : 0.0f;
    a1[j] = (__bf16)vv;
  }

  __bf16* hb = M.hbuf[wv];
  f32x4 zero4 = {0.0f, 0.0f, 0.0f, 0.0f};
  bf16x8 zero8;
  #pragma unroll
  for (int j = 0; j < 8; ++j) zero8[j] = (__bf16)0.0f;

  f32x4 acc2[4] = {zero4, zero4, zero4, zero4};

  #pragma unroll
  for (int p = 0; p < 4; ++p){
    #pragma unroll
    for (int c4 = 0; c4 < 4; ++c4){
      int ct = p*4 + c4;
      bf16x8 bw = zero8;
      if (lane < 32) bw = *(const bf16x8*)&M.w1f[(ct*32 + lane)*8];
      f32x4 c1 = __builtin_amdgcn_mfma_f32_16x16x32_bf16(a1, bw, zero4, 0, 0, 0);
      int f = c4*16 + m;
      float bb = M.b1s[p*64 + f];
      #pragma unroll
      for (int i = 0; i < 4; ++i){
        float h = tanh_f(c1[i] + bb);
        hb[(q*4 + i)*72 + f] = (__bf16)h;
      }
    }
    #pragma unroll
    for (int kb = 0; kb < 2; ++kb){
      bf16x8 a2 = *(const bf16x8*)&hb[m*72 + q*8 + kb*32];
      #pragma unroll
      for (int ct = 0; ct < 4; ++ct){
        bf16x8 bw2 = *(const bf16x8*)&M.w2f[(((p*2 + kb)*4 + ct)*64 + lane)*8];
        acc2[ct] = __builtin_amdgcn_mfma_f32_16x16x32_bf16(a2, bw2, acc2[ct], 0, 0, 0);
      }
    }
  }

  #pragma unroll
  for (int ct = 0; ct < 4; ++ct){
    int f = ct*16 + m;
    float bb = M.b2s[f];
    #pragma unroll
    for (int i = 0; i < 4; ++i){
      float h = tanh_f(acc2[ct][i] + bb);
      hb[(q*4 + i)*72 + f] = (__bf16)h;
    }
  }

  float z0 = M.b3s[2*q], z1 = M.b3s[2*q + 1];
  #pragma unroll
  for (int kb3 = 0; kb3 < 8; ++kb3){
    bf16x8 hv8 = *(const bf16x8*)&hb[m*72 + kb3*8];
    #pragma unroll
    for (int j = 0; j < 8; ++j){
      float hv = (float)hv8[j];
      int k = kb3*8 + j;
      z0 = fmaf(hv, M.w3s[k*8 + 2*q],     z0);
      z1 = fmaf(hv, M.w3s[k*8 + 2*q + 1], z1);
    }
  }
  float2 outp = make_float2(sigmoid_f(z0), sigmoid_f(z1));
  *(float2*)&params2[(size_t)rho*8 + 2*q] = outp;
}

// flat b-major elementwise epilogue: everything coalesced
__global__ __launch_bounds__(256) void final_kernel(const float* __restrict__ ws,
                                                    float* __restrict__ out){
  int rho = blockIdx.x*256 + threadIdx.x;
  if (rho >= NT) return;
  const float* wuT = ws;
  const float* wdT = ws + (size_t)NT;
  const float* params2 = ws + 2*(size_t)NT;
  const float* pT  = ws + 10*(size_t)NT;

  float p  = pT[rho];
  float wu = wuT[rho], wd = wdT[rho];
  const float4* pp = (const float4*)(params2 + (size_t)rho*8);
  float4 p0 = pp[0], p1 = pp[1];
  // reference calls _runoff(wu, wd, wl, p, wum, wdm, wlm, b, c):
  //   state wd lands in "wl" slot; param wdm in "wlm" slot; param wlm in "wdm" slot
  float wum   = fmaf(p0.x, 19.9f, 0.1f);
  float wlm_s = fmaf(p0.z, 30.0f, 60.0f);
  float wdm_s = fmaf(p0.y, 60.0f, 60.0f);
  float cc = fmaf(p1.x, 0.19f, 0.01f);
  float bcoef = fmaf(p0.w, 0.30f, 0.10f);
  float wt = wum + wlm_s + wdm_s;
  float xu = wu / wt;
  float xd = wd / wt;
  float s  = cc*xu*xu + bcoef*xd*xd;
  float ps = p - s;
  float runoff = hside(ps)*ps;
  float k1p = fmaf(p1.y, 0.69f, 0.01f);
  float k2p = fmaf(p1.z, 0.69f, 0.01f);
  float k3p = fmaf(p1.w, 0.89f, 0.01f);
  float sr  = k1p*runoff;
  float itf = k2p*(runoff - sr);
  float bf  = k3p*(runoff - sr - itf);
  out[rho] = sr + 0.5f*itf + 0.25f*bf;
}

extern "C" void kernel_launch(void* const* d_in, const int* in_sizes, int n_in,
                              void* d_out, int out_size, void* d_ws, size_t ws_size,
                              hipStream_t stream) {
  const float* in = (const float*)d_in[0];
  const float* w1 = (const float*)d_in[1];
  const float* b1 = (const float*)d_in[2];
  const float* w2 = (const float*)d_in[3];
  const float* b2 = (const float*)d_in[4];
  const float* w3 = (const float*)d_in[5];
  const float* b3 = (const float*)d_in[6];
  float* out = (float*)d_out;
  float* ws  = (float*)d_ws;

  fused_kernel<<<NT/128 + 8, 576, 0, stream>>>(in, w1, b1, w2, b2, w3, b3, ws);
  final_kernel<<<NT/256,     256, 0, stream>>>(ws, out);
}